// Round 1
// baseline (184.709 us; speedup 1.0000x reference)
//
#include <hip/hip_runtime.h>

// Problem constants (reference: B=4096, C=1000, T_THR=2, T_KD=20, ALPHA=0.8)
constexpr int   B        = 4096;
constexpr int   C        = 1000;
constexpr float ALPHA    = 0.8f;
constexpr float INV_TKD  = 0.05f;    // 1/20
constexpr float TKD2     = 400.0f;   // 20*20
constexpr float INV_TTHR = 0.5f;     // 1/2
constexpr float SENT     = -1e30f;   // finite sentinel for invalid lanes

// ---------------------------------------------------------------------------
// Kernel 1: one wave (64 lanes) per sample row. Each lane holds 16 elements
// (4 x float4; row byte stride 4000 is 16B aligned). Streams the 8 teachers
// once, accumulates the mimic row in registers, and emits per-row
// CE, G = sum_t thr_t * tgt_t * (KD_t - CE), and rowmax over the 8 teachers.
// ---------------------------------------------------------------------------
__global__ __launch_bounds__(256) void row_kernel(
    const float* __restrict__ T0, const float* __restrict__ T1,
    const float* __restrict__ T2, const float* __restrict__ T3,
    const float* __restrict__ T4, const float* __restrict__ T5,
    const float* __restrict__ T6, const float* __restrict__ T7,
    const float* __restrict__ S,  const int* __restrict__ TGT,
    float* __restrict__ ws_ce, float* __restrict__ ws_g, float* __restrict__ ws_m)
{
    const int lane = threadIdx.x & 63;
    const int wid  = threadIdx.x >> 6;
    const int b    = blockIdx.x * 4 + wid;            // grid = B/4 blocks
    const size_t base = (size_t)b * C;

    const int tgt   = TGT[b];                         // wave-uniform
    const int uidx  = ((tgt >> 8) << 2) | (tgt & 3);  // register slot of target elem
    const int slane = (tgt >> 2) & 63;                // lane that owns it

    // guarded 4x float4 row load; lanes past C get finite sentinel
    auto load_row = [&](const float* __restrict__ p, float (&v)[16]) {
        const float4* p4 = (const float4*)(p + base);
#pragma unroll
        for (int k = 0; k < 4; ++k) {
            if (k < 3 || lane < 58) {       // k=3 covers c in [768,1000)
                float4 f = p4[lane + 64 * k];
                v[4*k+0] = f.x; v[4*k+1] = f.y; v[4*k+2] = f.z; v[4*k+3] = f.w;
            } else {
                v[4*k+0] = SENT; v[4*k+1] = SENT; v[4*k+2] = SENT; v[4*k+3] = SENT;
            }
        }
    };

    // exact target-logit extraction: uniform-index select + one shuffle
    auto extract = [&](const float (&v)[16]) -> float {
        float cand = 0.0f;
#pragma unroll
        for (int i = 0; i < 16; ++i) cand = (i == uidx) ? v[i] : cand;
        return __shfl(cand, slane, 64);
    };

    // ---------------- student pass ----------------
    float sv[16];
    load_row(S, sv);

    float smax = SENT;
#pragma unroll
    for (int i = 0; i < 16; ++i) smax = fmaxf(smax, sv[i]);
#pragma unroll
    for (int m = 1; m < 64; m <<= 1) smax = fmaxf(smax, __shfl_xor(smax, m, 64));

#pragma unroll
    for (int i = 0; i < 16; ++i) sv[i] -= smax;       // sv now = s - max_s

    float z1 = 0.0f, zT = 0.0f;
#pragma unroll
    for (int i = 0; i < 16; ++i) {
        z1 += __expf(sv[i]);
        zT += __expf(sv[i] * INV_TKD);
    }
#pragma unroll
    for (int m = 1; m < 64; m <<= 1) {
        z1 += __shfl_xor(z1, m, 64);
        zT += __shfl_xor(zT, m, 64);
    }
    const float logZ1 = __logf(z1);
    const float logZT = __logf(zT);
    const float sd_tgt = extract(sv);
    const float ce = logZ1 - sd_tgt;                  // cross-entropy of student

    // ---------------- teacher passes ----------------
    float acc[16];
#pragma unroll
    for (int i = 0; i < 16; ++i) acc[i] = 0.0f;

    float rowmax8 = SENT;          // max over the 8 real teachers (this row)
    float mx = 0.0f, s1 = 0.0f, s2 = 0.0f;   // online softmax over 9 teachers

    // process one teacher-row worth of values; returns its top1
    auto process_vals = [&](const float (&v)[16]) -> float {
        // top-2 over the row
        float m1 = SENT, m2 = SENT;
#pragma unroll
        for (int i = 0; i < 16; ++i) {
            float x = v[i];
            if (x > m1) { m2 = m1; m1 = x; } else { m2 = fmaxf(m2, x); }
        }
#pragma unroll
        for (int m = 1; m < 64; m <<= 1) {
            float o1 = __shfl_xor(m1, m, 64);
            float o2 = __shfl_xor(m2, m, 64);
            float n1 = fmaxf(m1, o1);
            float n2 = fmaxf(fminf(m1, o1), (m1 >= o1) ? m2 : o2);
            m1 = n1; m2 = n2;
        }
        const float tval = extract(v);

        // softened-teacher moments: Z = sum e, Ssum = sum e*(s - max_s)
        float Z = 0.0f, Ssum = 0.0f;
#pragma unroll
        for (int i = 0; i < 16; ++i) {
            float e = __expf((v[i] - m1) * INV_TKD);
            Z    += e;
            Ssum += e * sv[i];
        }
#pragma unroll
        for (int m = 1; m < 64; m <<= 1) {
            Z    += __shfl_xor(Z, m, 64);
            Ssum += __shfl_xor(Ssum, m, 64);
        }

        const float kd = TKD2 * (logZT - INV_TKD * (Ssum / Z));
        const float margin = (tval == m1) ? (m1 - m2) : 0.0f;
        const float u = tval * (kd - ce);

        // online softmax over teacher axis (margins >= 0, so mx init 0 is safe)
        const float nmx = fmaxf(mx, margin);
        const float sc  = __expf((mx - nmx) * INV_TTHR);
        const float ee  = __expf((margin - nmx) * INV_TTHR);
        s1 = s1 * sc + ee;
        s2 = s2 * sc + ee * u;
        mx = nmx;
        return m1;
    };

    auto process_teacher = [&](const float* __restrict__ p) {
        float v[16];
        load_row(p, v);
#pragma unroll
        for (int i = 0; i < 16; ++i) acc[i] += v[i];
        rowmax8 = fmaxf(rowmax8, process_vals(v));
    };

    process_teacher(T0); process_teacher(T1); process_teacher(T2); process_teacher(T3);
    process_teacher(T4); process_teacher(T5); process_teacher(T6); process_teacher(T7);

    // mimic = mean of the 8 teachers (9th branch; not part of max_preds)
#pragma unroll
    for (int i = 0; i < 16; ++i) acc[i] *= 0.125f;
    process_vals(acc);

    if (lane == 0) {
        ws_ce[b] = ce;
        ws_g[b]  = s2 / s1;
        ws_m[b]  = rowmax8;
    }
}

// ---------------------------------------------------------------------------
// Kernel 2: single block. max_preds over rows, then f64-accumulated mean of
// CE_b + (ALPHA/max_preds) * G_b.
// ---------------------------------------------------------------------------
__global__ __launch_bounds__(256) void fin_kernel(
    const float* __restrict__ ce, const float* __restrict__ g,
    const float* __restrict__ m, float* __restrict__ out)
{
    __shared__ float  smax[256];
    __shared__ double ssum[256];
    const int tid = threadIdx.x;

    float mx = SENT;
    for (int i = tid; i < B; i += 256) mx = fmaxf(mx, m[i]);
    smax[tid] = mx;
    __syncthreads();
    for (int s = 128; s > 0; s >>= 1) {
        if (tid < s) smax[tid] = fmaxf(smax[tid], smax[tid + s]);
        __syncthreads();
    }
    const float scale = ALPHA / smax[0];

    double acc = 0.0;
    for (int i = tid; i < B; i += 256) acc += (double)(ce[i] + g[i] * scale);
    ssum[tid] = acc;
    __syncthreads();
    for (int s = 128; s > 0; s >>= 1) {
        if (tid < s) ssum[tid] += ssum[tid + s];
        __syncthreads();
    }
    if (tid == 0) out[0] = (float)(ssum[0] * (1.0 / (double)B));
}

extern "C" void kernel_launch(void* const* d_in, const int* in_sizes, int n_in,
                              void* d_out, int out_size, void* d_ws, size_t ws_size,
                              hipStream_t stream)
{
    const float* T0 = (const float*)d_in[0];
    const float* T1 = (const float*)d_in[1];
    const float* T2 = (const float*)d_in[2];
    const float* T3 = (const float*)d_in[3];
    const float* T4 = (const float*)d_in[4];
    const float* T5 = (const float*)d_in[5];
    const float* T6 = (const float*)d_in[6];
    const float* T7 = (const float*)d_in[7];
    const float* S  = (const float*)d_in[8];
    const int*   TG = (const int*)d_in[9];

    float* ws = (float*)d_ws;
    float* ws_ce = ws;
    float* ws_g  = ws + B;
    float* ws_m  = ws + 2 * B;

    row_kernel<<<B / 4, 256, 0, stream>>>(T0, T1, T2, T3, T4, T5, T6, T7,
                                          S, TG, ws_ce, ws_g, ws_m);
    fin_kernel<<<1, 256, 0, stream>>>(ws_ce, ws_g, ws_m, (float*)d_out);
}